// Round 6
// baseline (19427.045 us; speedup 1.0000x reference)
//
#include <hip/hip_runtime.h>

typedef unsigned short u16;
typedef unsigned int u32;
typedef short bs8 __attribute__((ext_vector_type(8)));
typedef float f4_t __attribute__((ext_vector_type(4)));

#define NB   32
#define TSEQ 512
#define TENC 1024
#define HD   1024
#define VOC  512
#define FS   32   // flag stride in dwords (128B)

#define AS1 __attribute__((address_space(1)))
#define AS3 __attribute__((address_space(3)))

__device__ __forceinline__ float b2f(u16 u) {
  union { u32 i; float f; } x; x.i = ((u32)u) << 16; return x.f;
}
__device__ __forceinline__ u16 f2b(float f) {
  union { float ff; u32 i; } x; x.ff = f;
  u32 r = x.i + 0x7fff + ((x.i >> 16) & 1);   // RNE
  return (u16)(r >> 16);
}
__device__ __forceinline__ float inF(const void* p, size_t i, int bf) {
  return bf ? b2f(((const u16*)p)[i]) : ((const float*)p)[i];
}
__device__ __forceinline__ void inF4(const void* p, size_t i, int bf, float* o) {
  if (bf) {
    ushort4 u = *reinterpret_cast<const ushort4*>((const u16*)p + i);
    o[0] = b2f(u.x); o[1] = b2f(u.y); o[2] = b2f(u.z); o[3] = b2f(u.w);
  } else {
    float4 v = *reinterpret_cast<const float4*>((const float*)p + i);
    o[0] = v.x; o[1] = v.y; o[2] = v.z; o[3] = v.w;
  }
}
__device__ __forceinline__ void outF(void* p, size_t i, float v, int bf) {
  if (bf) ((u16*)p)[i] = f2b(v);
  else ((float*)p)[i] = v;
}
__device__ __forceinline__ void gld16(const void* g, void* l) {
  __builtin_amdgcn_global_load_lds((const AS1 u32*)g, (AS3 u32*)l, 16, 0, 0);
}
// coherence-point (sc1) accesses: relaxed agent-scope atomics bypass the XCD L2
__device__ __forceinline__ u32 ucLoad(u32* p) {
  return __hip_atomic_load(p, __ATOMIC_RELAXED, __HIP_MEMORY_SCOPE_AGENT);
}
__device__ __forceinline__ void ucStore(u32* p, u32 v) {
  __hip_atomic_store(p, v, __ATOMIC_RELAXED, __HIP_MEMORY_SCOPE_AGENT);
}
__device__ __forceinline__ bs8 ldUC8(u32* p) {
  union { u32 d[4]; bs8 v; } u;
  u.d[0] = ucLoad(p); u.d[1] = ucLoad(p + 1);
  u.d[2] = ucLoad(p + 2); u.d[3] = ucLoad(p + 3);
  return u.v;
}

// ---------------- dtype detect ----------------
__global__ void k_detect(const u32* __restrict__ w, int* __restrict__ flag) {
  __shared__ int cnt;
  if (threadIdx.x == 0) cnt = 0;
  __syncthreads();
  int c = 0;
  for (int i = threadIdx.x; i < 1024; i += 256) {
    u32 e = (w[i] >> 7) & 0xFF;
    if (e >= 100 && e <= 126) c++;
  }
  atomicAdd(&cnt, c);
  __syncthreads();
  if (threadIdx.x == 0) flag[0] = (cnt >= 512) ? 1 : 0;
}

// ---------------- generic f32|bf16 -> bf16 convert ----------------
__global__ __launch_bounds__(256) void k_f2bf(
    const void* __restrict__ in, u16* __restrict__ out, const int* __restrict__ flagp) {
  const int bf = flagp[0];
  size_t i = ((size_t)blockIdx.x * 256 + threadIdx.x) * 4;
  float v[4]; inF4(in, i, bf, v);
  ushort4 o; o.x = f2b(v[0]); o.y = f2b(v[1]); o.z = f2b(v[2]); o.w = f2b(v[3]);
  *reinterpret_cast<ushort4*>(&out[i]) = o;
}

// ---------------- embedding gather (with SOS prepend) -> bf16 x ----------------
__global__ __launch_bounds__(256) void k_embed(
    const int* __restrict__ labels, const void* __restrict__ emb,
    u16* __restrict__ x, const int* __restrict__ flagp) {
  const int bf = flagp[0];
  const int m = blockIdx.x;            // m = b*512 + t
  const int b = m >> 9, t = m & 511;
  const int lab = (t == 0) ? 0 : labels[b * 511 + t - 1];
  const size_t src = (size_t)lab * HD;
  const size_t dst = (size_t)m * HD;
  const int k = threadIdx.x * 4;
  float v[4]; inF4(emb, src + k, bf, v);
  ushort4 o; o.x = f2b(v[0]); o.y = f2b(v[1]); o.z = f2b(v[2]); o.w = f2b(v[3]);
  *reinterpret_cast<ushort4*>(&x[dst + k]) = o;
}

// ---------------- enc transpose: [b][t][h] -> [b][h][t] bf16 ----------------
__global__ __launch_bounds__(256) void k_transpose(
    const void* __restrict__ enc, u16* __restrict__ encT, const int* __restrict__ flagp) {
  const int bf = flagp[0];
  __shared__ float tile[32][33];
  const int b = blockIdx.z, t0 = blockIdx.x * 32, h0 = blockIdx.y * 32;
  const int i = threadIdx.x >> 5, j = threadIdx.x & 31;
  const size_t base = (size_t)b * (TENC * HD);
#pragma unroll
  for (int rr = 0; rr < 4; rr++) {
    int r = i + rr * 8;
    tile[r][j] = inF(enc, base + (size_t)(t0 + r) * HD + h0 + j, bf);
  }
  __syncthreads();
#pragma unroll
  for (int rr = 0; rr < 4; rr++) {
    int r = i + rr * 8;
    encT[base + (size_t)(h0 + r) * TENC + t0 + j] = f2b(tile[j][r]);
  }
}

// ---------------- MFMA GEMM: C[m][n] = act(sum_k A[m][k]*B[n][k] + bias[n]) ----------------
// cmode: 0 = bf16 row-major, 1 = f32 row-major, 2 = bf16 t-major ((row&511)*32+(row>>9))
__global__ __launch_bounds__(256) void k_mfma_gemm(
    const u16* __restrict__ A, const u16* __restrict__ Bm, int K, int lda, int ldb,
    long strideA, long strideB, long strideC,
    void* __restrict__ C, int ldc, int cmode, int act,
    const void* __restrict__ bias, const int* __restrict__ flagp) {
  const int bf = flagp[0];
  __shared__ u16 lsA[8192];
  __shared__ u16 lsB[8192];
  const int tid = threadIdx.x;
  const int l = tid & 63, w = tid >> 6;
  const int wr = w >> 1, wc = w & 1;
  const long m0 = (long)blockIdx.x * 128;
  const long n0 = (long)blockIdx.y * 128;
  const long bz = blockIdx.z;
  const u16* Ab = A + bz * strideA;
  const u16* Bb = Bm + bz * strideB;

  f4_t acc[4][4] = {};
  const int srow = w * 8 + (l >> 3);
  const int schx = (l & 7) * 16;

  for (int kt = 0; kt < K; kt += 64) {
#pragma unroll
    for (int i = 0; i < 4; i++) {
      const int row = i * 32 + srow;
      const char* ga = (const char*)(Ab + (m0 + row) * (long)lda + kt)
                       + (schx ^ ((row & 7) << 4));
      gld16(ga, (char*)lsA + i * 4096 + w * 1024);
    }
#pragma unroll
    for (int i = 0; i < 4; i++) {
      const int row = i * 32 + srow;
      const char* gb = (const char*)(Bb + (n0 + row) * (long)ldb + kt)
                       + (schx ^ ((row & 7) << 4));
      gld16(gb, (char*)lsB + i * 4096 + w * 1024);
    }
    __syncthreads();
#pragma unroll
    for (int h = 0; h < 2; h++) {
      bs8 af[4], bfr[4];
#pragma unroll
      for (int i = 0; i < 4; i++) {
        const int row = wr * 64 + i * 16 + (l & 15);
        const int byt = row * 128 + (((h * 64) + ((l >> 4) * 16)) ^ ((row & 7) << 4));
        af[i] = *(const bs8*)((const char*)lsA + byt);
      }
#pragma unroll
      for (int j = 0; j < 4; j++) {
        const int row = wc * 64 + j * 16 + (l & 15);
        const int byt = row * 128 + (((h * 64) + ((l >> 4) * 16)) ^ ((row & 7) << 4));
        bfr[j] = *(const bs8*)((const char*)lsB + byt);
      }
#pragma unroll
      for (int i = 0; i < 4; i++)
#pragma unroll
        for (int j = 0; j < 4; j++)
          acc[i][j] = __builtin_amdgcn_mfma_f32_16x16x32_bf16(af[i], bfr[j], acc[i][j], 0, 0, 0);
    }
    __syncthreads();
  }

  float bv[4] = {0.f, 0.f, 0.f, 0.f};
  if (bias) {
#pragma unroll
    for (int j = 0; j < 4; j++)
      bv[j] = inF(bias, (size_t)(n0 + wc * 64 + j * 16 + (l & 15)), bf);
  }
#pragma unroll
  for (int i = 0; i < 4; i++) {
#pragma unroll
    for (int j = 0; j < 4; j++) {
      const long rowb = m0 + wr * 64 + i * 16 + ((l >> 4) * 4);
      const long col = n0 + wc * 64 + j * 16 + (l & 15);
#pragma unroll
      for (int r = 0; r < 4; r++) {
        float v = acc[i][j][r] + bv[j];
        if (act == 1) v = tanhf(v);
        const long row = rowb + r;
        if (cmode == 0) {
          ((u16*)C)[bz * strideC + row * (long)ldc + col] = f2b(v);
        } else if (cmode == 1) {
          ((float*)C)[bz * strideC + row * (long)ldc + col] = v;
        } else {
          ((u16*)C)[((long)(row & 511) * 32 + (row >> 9)) * (long)ldc + col] = f2b(v);
        }
      }
    }
  }
}

// ---------------- masked softmax over T_ENC (in-place bf16) ----------------
__global__ __launch_bounds__(256) void k_softmax(
    u16* __restrict__ S, const int* __restrict__ lens) {
  const int m = blockIdx.x;
  const int b = m >> 9;
  const int len = lens[b];
  const int tid = threadIdx.x;
  const size_t base = (size_t)m * TENC;
  float v[4];
  float mx = -1e30f;
#pragma unroll
  for (int i = 0; i < 4; i++) {
    int j = tid + i * 256;
    float s = b2f(S[base + j]);
    v[i] = (j < len) ? s : -1e30f;
    mx = fmaxf(mx, v[i]);
  }
  __shared__ float red[8];
  for (int o = 32; o; o >>= 1) mx = fmaxf(mx, __shfl_xor(mx, o, 64));
  if ((tid & 63) == 0) red[tid >> 6] = mx;
  __syncthreads();
  mx = fmaxf(fmaxf(red[0], red[1]), fmaxf(red[2], red[3]));
  float e[4]; float sum = 0.f;
#pragma unroll
  for (int i = 0; i < 4; i++) {
    e[i] = (v[i] > -1e29f) ? expf(v[i] - mx) : 0.f;
    sum += e[i];
  }
  for (int o = 32; o; o >>= 1) sum += __shfl_xor(sum, o, 64);
  __shared__ float red2[8];
  if ((tid & 63) == 0) red2[tid >> 6] = sum;
  __syncthreads();
  sum = red2[0] + red2[1] + red2[2] + red2[3];
  const float inv = 1.f / sum;
#pragma unroll
  for (int i = 0; i < 4; i++) S[base + tid + i * 256] = f2b(e[i] * inv);
}

// ---------------- pack weights into per-block MFMA fragment order ----------------
// virtual col v -> feature f=v>>2, slot=v&3 (r, z, n_ih, n_hh)
// fused=0 (L0): 64 blks x 64 cols, K=1024 (Whh; slot3 zero)  [blk][c16(4)][ks(32)][l][8]
// fused=1 (L1): 128 blks x 32 cols, K=2048 ([Wih;Whh])        [blk][c16(2)][ks(64)][l][8]
__global__ __launch_bounds__(256) void k_packw(
    const void* __restrict__ Wih, const void* __restrict__ Whh,
    u16* __restrict__ out, int fused, const int* __restrict__ flagp) {
  const int bf = flagp[0];
  const long idx = (long)blockIdx.x * 256 + threadIdx.x;
  const int l = (int)(idx & 63);
  int ks, c16, blk, v;
  if (fused) {
    ks = (int)((idx >> 6) & 63); c16 = (int)((idx >> 12) & 1); blk = (int)(idx >> 13);
    v = blk * 32 + c16 * 16 + (l & 15);
  } else {
    ks = (int)((idx >> 6) & 31); c16 = (int)((idx >> 11) & 3); blk = (int)(idx >> 13);
    v = blk * 64 + c16 * 16 + (l & 15);
  }
  const int f = v >> 2, slot = v & 3;
  const int k = ks * 32 + ((l >> 4) << 3);
  const void* W = Whh; long row = 0; bool zero = false; int kk = k;
  if (!fused) {
    if (slot == 0) row = f;
    else if (slot == 1) row = 1024 + f;
    else if (slot == 2) row = 2048 + f;
    else zero = true;
  } else {
    const bool xp = (k < 1024); kk = k & 1023;
    W = xp ? Wih : Whh;
    if (slot == 0) row = f;
    else if (slot == 1) row = 1024 + f;
    else if (slot == 2) { row = 2048 + f; zero = !xp; }
    else { row = 2048 + f; zero = xp; }
  }
  u16 o[8];
#pragma unroll
  for (int e = 0; e < 8; e++)
    o[e] = zero ? (u16)0 : f2b(inF(W, (size_t)row * 1024 + kk + e, bf));
  ushort4* dst = (ushort4*)(out + idx * 8);
  dst[0] = make_ushort4(o[0], o[1], o[2], o[3]);
  dst[1] = make_ushort4(o[4], o[5], o[6], o[7]);
}

// ---------------- persistent 2-layer GRU (fence-free sc1 handshake) ----------------
__device__ __forceinline__ void waitflags(u32* flags, int base, int cnt, int target, int tid) {
  if (target > 0) {
    if (tid < 64) {
      int guard = 0;
      while (1) {
        bool ok = true;
        for (int i = tid; i < cnt; i += 64)
          ok &= ((int)ucLoad(flags + (size_t)(base + i) * FS) >= target);
        if (__all(ok)) break;
        if (++guard > (1 << 20)) break;   // hang-safety cap
        __builtin_amdgcn_s_sleep(2);
      }
    }
  }
  __syncthreads();
}

// grid 192 x 512thr. Blocks 0-63: L0 (16 feats, K=1024, Whh in LDS).
// Blocks 64-191: L1 (8 feats, K=2048 fused [y0;h1], W in LDS).
// h exchanged as bf16x2 dwords [b][512] via sc1 atomics; double-buffered parity.
__global__ void __launch_bounds__(512, 1) k_gru_persist(
    const u16* __restrict__ xp0, const u16* __restrict__ wpk0, const u16* __restrict__ wpk1,
    const void* __restrict__ bhh0, const void* __restrict__ bih1, const void* __restrict__ bhh1,
    u16* __restrict__ y1, u32* h0buf, u32* h1buf, u32* flags,
    const int* __restrict__ flagp) {
  extern __shared__ char smem[];
  u16* Wl = (u16*)smem;                 // 128 KB weight slice
  float* red = (float*)(smem + 131072); // 12 KB kh-reduction
  const int bf = flagp[0];
  const int tid = threadIdx.x, l = tid & 63, w = tid >> 6;
  const int g = blockIdx.x;
  const bool isL0 = (g < 64);
  const int gg = isL0 ? g : g - 64;

  {  // stage 128KB weight slice into LDS (linear DMA)
    const char* wsrc = isL0 ? (const char*)(wpk0 + (size_t)gg * 65536)
                            : (const char*)(wpk1 + (size_t)gg * 65536);
#pragma unroll
    for (int i = 0; i < 16; i++) {
      const int off = i * 8192 + w * 1024;
      gld16(wsrc + off + l * 16, smem + off);
    }
  }
  __syncthreads();

  if (isL0) {
    const int nh = w & 3, kh = w >> 2;
    const int fl = (l & 15) >> 2;
    const int F = gg * 16 + nh * 4 + fl;
    const int bl0 = (l & 48) | (fl << 2);
    float br = 0.f, bz = 0.f, bn = 0.f;
    if (kh == 0) {
      br = inF(bhh0, (size_t)F, bf);
      bz = inF(bhh0, (size_t)(1024 + F), bf);
      bn = inF(bhh0, (size_t)(2048 + F), bf);
    }
    float hprev[2][4] = {{0.f,0.f,0.f,0.f},{0.f,0.f,0.f,0.f}};
    for (int t = 0; t < TSEQ; t++) {
      waitflags(flags, 0, 64, t, tid);        // own group finished t-1
      waitflags(flags, 64, 128, t - 1, tid);  // L1 done reading y0(t-2) buffer
      u32* hr = h0buf + (size_t)(t & 1) * 16384;
      u32* hw = h0buf + (size_t)((t + 1) & 1) * 16384;
      f4_t S[2] = {};
#pragma unroll 4
      for (int ksl = 0; ksl < 16; ksl++) {
        const int ks = kh * 16 + ksl;
        const int kd = (ks * 32 + ((l >> 4) << 3)) >> 1;
        const bs8 a0 = ldUC8(hr + (l & 15) * 512 + kd);
        const bs8 a1 = ldUC8(hr + (16 + (l & 15)) * 512 + kd);
        const bs8 bb = *(const bs8*)(Wl + (((size_t)(nh * 32 + ks) * 64 + l) << 3));
        S[0] = __builtin_amdgcn_mfma_f32_16x16x32_bf16(a0, bb, S[0], 0, 0, 0);
        S[1] = __builtin_amdgcn_mfma_f32_16x16x32_bf16(a1, bb, S[1], 0, 0, 0);
      }
      if (kh == 1) {
#pragma unroll
        for (int mt = 0; mt < 2; mt++)
          *(f4_t*)&red[((nh * 2 + mt) * 64 + l) * 4] = S[mt];
      }
      __syncthreads();
      if (kh == 0) {
#pragma unroll
        for (int mt = 0; mt < 2; mt++)
          S[mt] += *(const f4_t*)&red[((nh * 2 + mt) * 64 + l) * 4];
#pragma unroll
        for (int mt = 0; mt < 2; mt++) {
#pragma unroll
          for (int r = 0; r < 4; r++) {
            const int b = mt * 16 + ((l >> 4) << 2) + r;
            const float hrv = __shfl(S[mt][r], bl0);
            const float hzv = __shfl(S[mt][r], bl0 + 1);
            const float hnv = __shfl(S[mt][r], bl0 + 2);
            const long xb = (long)t * 98304 + (long)b * 3072 + F;
            const float xr = b2f(xp0[xb]);
            const float xz = b2f(xp0[xb + 1024]);
            const float xn = b2f(xp0[xb + 2048]);
            const float rr = 1.f / (1.f + expf(-(xr + hrv + br)));
            const float zz = 1.f / (1.f + expf(-(xz + hzv + bz)));
            const float nn = tanhf(xn + rr * (hnv + bn));
            const float hv = (1.f - zz) * nn + zz * hprev[mt][r];
            hprev[mt][r] = hv;
            const u32 hb16 = (u32)f2b(hv);
            const u32 part = (u32)__shfl_xor((int)hb16, 4);
            if ((l & 15) == 0 || (l & 15) == 8)
              ucStore(hw + b * 512 + (F >> 1), hb16 | (part << 16));
          }
        }
      }
      asm volatile("s_waitcnt vmcnt(0)" ::: "memory");  // data at coherence point
      __syncthreads();
      if (tid == 0) ucStore(flags + (size_t)g * FS, (u32)(t + 1));
    }
  } else {
    const int nh = w & 1, kh = w >> 1;
    const int fl = (l & 15) >> 2;
    const int F = gg * 8 + nh * 4 + fl;
    const int bl0 = (l & 48) | (fl << 2);
    float br = 0.f, bz = 0.f, bxn = 0.f, bhn = 0.f;
    if (kh == 0) {
      br = inF(bih1, (size_t)F, bf) + inF(bhh1, (size_t)F, bf);
      bz = inF(bih1, (size_t)(1024 + F), bf) + inF(bhh1, (size_t)(1024 + F), bf);
      bxn = inF(bih1, (size_t)(2048 + F), bf);
      bhn = inF(bhh1, (size_t)(2048 + F), bf);
    }
    float hprev[2][4] = {{0.f,0.f,0.f,0.f},{0.f,0.f,0.f,0.f}};
    for (int t = 0; t < TSEQ; t++) {
      waitflags(flags, 0, 64, t + 1, tid);    // y0(t) ready
      waitflags(flags, 64, 128, t, tid);      // own group finished t-1
      u32* y0r = h0buf + (size_t)((t + 1) & 1) * 16384;
      u32* h1r = h1buf + (size_t)(t & 1) * 16384;
      u32* hw = h1buf + (size_t)((t + 1) & 1) * 16384;
      f4_t S[2] = {};
#pragma unroll 4
      for (int ksl = 0; ksl < 16; ksl++) {
        const int ks = kh * 16 + ksl;
        u32* Ar = (ks < 32) ? y0r : h1r;
        const int kd = ((ks & 31) * 32 + ((l >> 4) << 3)) >> 1;
        const bs8 a0 = ldUC8(Ar + (l & 15) * 512 + kd);
        const bs8 a1 = ldUC8(Ar + (16 + (l & 15)) * 512 + kd);
        const bs8 bb = *(const bs8*)(Wl + (((size_t)(nh * 64 + ks) * 64 + l) << 3));
        S[0] = __builtin_amdgcn_mfma_f32_16x16x32_bf16(a0, bb, S[0], 0, 0, 0);
        S[1] = __builtin_amdgcn_mfma_f32_16x16x32_bf16(a1, bb, S[1], 0, 0, 0);
      }
      if (kh > 0) {
#pragma unroll
        for (int mt = 0; mt < 2; mt++)
          *(f4_t*)&red[(((kh - 1) * 4 + nh * 2 + mt) * 64 + l) * 4] = S[mt];
      }
      __syncthreads();
      if (kh == 0) {
#pragma unroll
        for (int kk = 0; kk < 3; kk++)
#pragma unroll
          for (int mt = 0; mt < 2; mt++)
            S[mt] += *(const f4_t*)&red[((kk * 4 + nh * 2 + mt) * 64 + l) * 4];
#pragma unroll
        for (int mt = 0; mt < 2; mt++) {
#pragma unroll
          for (int r = 0; r < 4; r++) {
            const int b = mt * 16 + ((l >> 4) << 2) + r;
            const float rs = __shfl(S[mt][r], bl0);
            const float zs = __shfl(S[mt][r], bl0 + 1);
            const float xnp = __shfl(S[mt][r], bl0 + 2);
            const float hnp = __shfl(S[mt][r], bl0 + 3);
            const float rr = 1.f / (1.f + expf(-(rs + br)));
            const float zz = 1.f / (1.f + expf(-(zs + bz)));
            const float nn = tanhf((xnp + bxn) + rr * (hnp + bhn));
            const float hv = (1.f - zz) * nn + zz * hprev[mt][r];
            hprev[mt][r] = hv;
            const u32 hb16 = (u32)f2b(hv);
            const u32 part = (u32)__shfl_xor((int)hb16, 4);
            if ((l & 15) == 0 || (l & 15) == 8)
              ucStore(hw + b * 512 + (F >> 1), hb16 | (part << 16));
            if ((l & 3) == 0)
              y1[((long)b * 512 + t) * 1024 + F] = f2b(hv);
          }
        }
      }
      asm volatile("s_waitcnt vmcnt(0)" ::: "memory");
      __syncthreads();
      if (tid == 0) ucStore(flags + (size_t)g * FS, (u32)(t + 1));
    }
  }
}

// ---------------- log_softmax over V ----------------
__global__ __launch_bounds__(256) void k_logsoftmax(
    const float* __restrict__ L, void* __restrict__ out, const int* __restrict__ flagp) {
  const int bf = flagp[0];
  const int m = blockIdx.x;
  const int tid = threadIdx.x;
  const size_t base = (size_t)m * VOC;
  float v0 = L[base + tid], v1 = L[base + tid + 256];
  float mx = fmaxf(v0, v1);
  __shared__ float red[8];
  for (int o = 32; o; o >>= 1) mx = fmaxf(mx, __shfl_xor(mx, o, 64));
  if ((tid & 63) == 0) red[tid >> 6] = mx;
  __syncthreads();
  mx = fmaxf(fmaxf(red[0], red[1]), fmaxf(red[2], red[3]));
  float s = expf(v0 - mx) + expf(v1 - mx);
  for (int o = 32; o; o >>= 1) s += __shfl_xor(s, o, 64);
  __shared__ float red2[8];
  if ((tid & 63) == 0) red2[tid >> 6] = s;
  __syncthreads();
  s = red2[0] + red2[1] + red2[2] + red2[3];
  const float lse = mx + logf(s);
  outF(out, base + tid, v0 - lse, bf);
  outF(out, base + tid + 256, v1 - lse, bf);
}

extern "C" void kernel_launch(void* const* d_in, const int* in_sizes, int n_in,
                              void* d_out, int out_size, void* d_ws, size_t ws_size,
                              hipStream_t stream) {
  const void* enc = d_in[0];
  const int* lens = (const int*)d_in[1];
  const int* labels = (const int*)d_in[2];
  const void* emb = d_in[3];
  const void* lin_in = d_in[4];
  const void* lin_out = d_in[5];
  const void* w_ih0 = d_in[6];
  const void* w_hh0 = d_in[7];
  const void* b_ih0 = d_in[8];
  const void* b_hh0 = d_in[9];
  const void* w_ih1 = d_in[10];
  const void* w_hh1 = d_in[11];
  const void* b_ih1 = d_in[12];
  const void* b_hh1 = d_in[13];
  const void* fc_w = d_in[14];
  const void* fc_b = d_in[15];

  char* ws = (char*)d_ws;
  const size_t SZ = (size_t)NB * TSEQ * HD * 2;   // 33,554,432
  int* flag = (int*)ws;
  u16* R0 = (u16*)(ws + 256);                     // x -> encT -> attn
  u16* R1 = (u16*)(ws + 256 + SZ);                // enc_bf -> wih0_bf
  u16* R2 = (u16*)(ws + 256 + 2 * SZ);            // combined -> [y1 | packs+small]
  char* R4 = ws + 256 + 4 * SZ;                   // scores+wli/wlo -> xp0 -> wfc+logits

  char* R2u = (char*)R2 + SZ;
  u16* wpk0 = (u16*)R2u;                          // 8 MB  (64 blk x 128KB)
  u16* wpk1 = (u16*)(R2u + 8388608);              // 16 MB (128 blk x 128KB)
  char* smallr = R2u + 25165824;
  u32* flagsbuf = (u32*)smallr;                   // 192*128B = 24576
  u32* h0buf = (u32*)(smallr + 24576);            // 2 x 64KB
  u32* h1buf = (u32*)(smallr + 24576 + 131072);   // 2 x 64KB
  const size_t small_bytes = 24576 + 262144;

  u16* scores = (u16*)R4;
  u16* wli = (u16*)(R4 + 35651584);
  u16* wlo = (u16*)(R4 + 37748736);
  u16* xp0 = (u16*)R4;                            // [t][b][3072] bf16, 96MB
  u16* wfc = (u16*)R4;                            // post-GRU, 1MB
  float* logits = (float*)(R4 + 1048576);         // post-GRU, 33.5MB f32

  k_detect<<<1, 256, 0, stream>>>((const u32*)emb, flag);
  k_embed<<<NB * TSEQ, 256, 0, stream>>>(labels, emb, R0, flag);
  k_f2bf<<<32768, 256, 0, stream>>>(enc, R1, flag);
  k_f2bf<<<1024, 256, 0, stream>>>(lin_in, wli, flag);
  k_f2bf<<<2048, 256, 0, stream>>>(lin_out, wlo, flag);

  // q = x @ lin_in^T -> combined right half
  k_mfma_gemm<<<dim3(128, 8, 1), 256, 0, stream>>>(
      R0, wli, HD, HD, HD, 0, 0, 0, (void*)(R2 + 1024), 2 * HD, 0, 0, nullptr, flag);
  // encT (x dead)
  k_transpose<<<dim3(32, 32, NB), 256, 0, stream>>>(enc, R0, flag);
  // scores[b] = q[b] @ enc_bf[b]^T
  k_mfma_gemm<<<dim3(4, 8, NB), 256, 0, stream>>>(
      R2 + 1024, R1, HD, 2 * HD, HD,
      (long)TSEQ * 2 * HD, (long)TENC * HD, (long)TSEQ * TENC,
      (void*)scores, TENC, 0, 0, nullptr, flag);
  k_softmax<<<NB * TSEQ, 256, 0, stream>>>(scores, lens);
  // mix[b] = w[b] @ encT[b]^T -> combined left half
  k_mfma_gemm<<<dim3(4, 8, NB), 256, 0, stream>>>(
      scores, R0, TENC, TENC, TENC,
      (long)TSEQ * TENC, (long)HD * TENC, (long)TSEQ * 2 * HD,
      (void*)R2, 2 * HD, 0, 0, nullptr, flag);
  // attn = tanh(combined @ lin_out^T) -> R0 row-major (encT dead)
  k_mfma_gemm<<<dim3(128, 8, 1), 256, 0, stream>>>(
      R2, wlo, 2 * HD, 2 * HD, 2 * HD, 0, 0, 0,
      (void*)R0, HD, 0, 1, nullptr, flag);

  // weight packs (combined dead -> R2 upper free)
  k_packw<<<2048, 256, 0, stream>>>(nullptr, w_hh0, wpk0, 0, flag);
  k_packw<<<4096, 256, 0, stream>>>(w_ih1, w_hh1, wpk1, 1, flag);
  // w_ih0 bf16 (enc_bf dead)
  k_f2bf<<<3072, 256, 0, stream>>>(w_ih0, R1, flag);
  // xp0 = attn @ w_ih0^T + b_ih0, t-major (overwrites scores/wli/wlo - all dead)
  k_mfma_gemm<<<dim3(128, 24, 1), 256, 0, stream>>>(
      R0, R1, HD, HD, HD, 0, 0, 0, (void*)xp0, 3 * HD, 2, 0, b_ih0, flag);

  // persistent GRU (fence-free, weights LDS-resident)
  hipMemsetAsync(smallr, 0, small_bytes, stream);
  hipFuncSetAttribute((const void*)k_gru_persist,
                      hipFuncAttributeMaxDynamicSharedMemorySize, 143360);
  u16* y1p = R2;
  void* args[] = {&xp0, &wpk0, &wpk1,
                  (void*)&b_hh0, (void*)&b_ih1, (void*)&b_hh1,
                  &y1p, &h0buf, &h1buf, &flagsbuf, &flag};
  hipLaunchCooperativeKernel((const void*)k_gru_persist, dim3(192), dim3(512),
                             args, 143360, stream);

  // logits = y1 @ fc_w^T + fc_b (xp0 dead)
  k_f2bf<<<512, 256, 0, stream>>>(fc_w, wfc, flag);
  k_mfma_gemm<<<dim3(128, 4, 1), 256, 0, stream>>>(
      R2, wfc, HD, HD, HD, 0, 0, 0, (void*)logits, VOC, 1, 0, fc_b, flag);
  k_logsoftmax<<<NB * TSEQ, 256, 0, stream>>>(logits, d_out, flag);
}

// Round 7
// 6111.626 us; speedup vs baseline: 3.1787x; 3.1787x over previous
//
#include <hip/hip_runtime.h>

typedef unsigned short u16;
typedef unsigned int u32;
typedef short bs8 __attribute__((ext_vector_type(8)));
typedef float f4_t __attribute__((ext_vector_type(4)));

#define NB   32
#define TSEQ 512
#define TENC 1024
#define HD   1024
#define VOC  512

#define AS1 __attribute__((address_space(1)))
#define AS3 __attribute__((address_space(3)))

__device__ __forceinline__ float b2f(u16 u) {
  union { u32 i; float f; } x; x.i = ((u32)u) << 16; return x.f;
}
__device__ __forceinline__ u16 f2b(float f) {
  union { float ff; u32 i; } x; x.ff = f;
  u32 r = x.i + 0x7fff + ((x.i >> 16) & 1);   // RNE
  return (u16)(r >> 16);
}
__device__ __forceinline__ float inF(const void* p, size_t i, int bf) {
  return bf ? b2f(((const u16*)p)[i]) : ((const float*)p)[i];
}
__device__ __forceinline__ void inF4(const void* p, size_t i, int bf, float* o) {
  if (bf) {
    ushort4 u = *reinterpret_cast<const ushort4*>((const u16*)p + i);
    o[0] = b2f(u.x); o[1] = b2f(u.y); o[2] = b2f(u.z); o[3] = b2f(u.w);
  } else {
    float4 v = *reinterpret_cast<const float4*>((const float*)p + i);
    o[0] = v.x; o[1] = v.y; o[2] = v.z; o[3] = v.w;
  }
}
__device__ __forceinline__ void outF(void* p, size_t i, float v, int bf) {
  if (bf) ((u16*)p)[i] = f2b(v);
  else ((float*)p)[i] = v;
}
__device__ __forceinline__ void gld16(const void* g, void* l) {
  __builtin_amdgcn_global_load_lds((const AS1 u32*)g, (AS3 u32*)l, 16, 0, 0);
}

// ---------------- dtype detect ----------------
__global__ void k_detect(const u32* __restrict__ w, int* __restrict__ flag) {
  __shared__ int cnt;
  if (threadIdx.x == 0) cnt = 0;
  __syncthreads();
  int c = 0;
  for (int i = threadIdx.x; i < 1024; i += 256) {
    u32 e = (w[i] >> 7) & 0xFF;
    if (e >= 100 && e <= 126) c++;
  }
  atomicAdd(&cnt, c);
  __syncthreads();
  if (threadIdx.x == 0) flag[0] = (cnt >= 512) ? 1 : 0;
}

// ---------------- generic f32|bf16 -> bf16 convert ----------------
__global__ __launch_bounds__(256) void k_f2bf(
    const void* __restrict__ in, u16* __restrict__ out, const int* __restrict__ flagp) {
  const int bf = flagp[0];
  size_t i = ((size_t)blockIdx.x * 256 + threadIdx.x) * 4;
  float v[4]; inF4(in, i, bf, v);
  ushort4 o; o.x = f2b(v[0]); o.y = f2b(v[1]); o.z = f2b(v[2]); o.w = f2b(v[3]);
  *reinterpret_cast<ushort4*>(&out[i]) = o;
}

// ---------------- embedding gather (with SOS prepend) -> bf16 x ----------------
__global__ __launch_bounds__(256) void k_embed(
    const int* __restrict__ labels, const void* __restrict__ emb,
    u16* __restrict__ x, const int* __restrict__ flagp) {
  const int bf = flagp[0];
  const int m = blockIdx.x;            // m = b*512 + t
  const int b = m >> 9, t = m & 511;
  const int lab = (t == 0) ? 0 : labels[b * 511 + t - 1];
  const size_t src = (size_t)lab * HD;
  const size_t dst = (size_t)m * HD;
  const int k = threadIdx.x * 4;
  float v[4]; inF4(emb, src + k, bf, v);
  ushort4 o; o.x = f2b(v[0]); o.y = f2b(v[1]); o.z = f2b(v[2]); o.w = f2b(v[3]);
  *reinterpret_cast<ushort4*>(&x[dst + k]) = o;
}

// ---------------- enc transpose: [b][t][h] -> [b][h][t] bf16 ----------------
__global__ __launch_bounds__(256) void k_transpose(
    const void* __restrict__ enc, u16* __restrict__ encT, const int* __restrict__ flagp) {
  const int bf = flagp[0];
  __shared__ float tile[32][33];
  const int b = blockIdx.z, t0 = blockIdx.x * 32, h0 = blockIdx.y * 32;
  const int i = threadIdx.x >> 5, j = threadIdx.x & 31;
  const size_t base = (size_t)b * (TENC * HD);
#pragma unroll
  for (int rr = 0; rr < 4; rr++) {
    int r = i + rr * 8;
    tile[r][j] = inF(enc, base + (size_t)(t0 + r) * HD + h0 + j, bf);
  }
  __syncthreads();
#pragma unroll
  for (int rr = 0; rr < 4; rr++) {
    int r = i + rr * 8;
    encT[base + (size_t)(h0 + r) * TENC + t0 + j] = f2b(tile[j][r]);
  }
}

// ---------------- MFMA GEMM: C[m][n] = act(sum_k A[m][k]*B[n][k] + bias[n]) ----------------
// cmode: 0 = bf16 row-major, 1 = f32 row-major, 2 = bf16 t-major ((row&511)*32+(row>>9))
__global__ __launch_bounds__(256) void k_mfma_gemm(
    const u16* __restrict__ A, const u16* __restrict__ Bm, int K, int lda, int ldb,
    long strideA, long strideB, long strideC,
    void* __restrict__ C, int ldc, int cmode, int act,
    const void* __restrict__ bias, const int* __restrict__ flagp) {
  const int bf = flagp[0];
  __shared__ u16 lsA[8192];
  __shared__ u16 lsB[8192];
  const int tid = threadIdx.x;
  const int l = tid & 63, w = tid >> 6;
  const int wr = w >> 1, wc = w & 1;
  const long m0 = (long)blockIdx.x * 128;
  const long n0 = (long)blockIdx.y * 128;
  const long bz = blockIdx.z;
  const u16* Ab = A + bz * strideA;
  const u16* Bb = Bm + bz * strideB;

  f4_t acc[4][4] = {};
  const int srow = w * 8 + (l >> 3);
  const int schx = (l & 7) * 16;

  for (int kt = 0; kt < K; kt += 64) {
#pragma unroll
    for (int i = 0; i < 4; i++) {
      const int row = i * 32 + srow;
      const char* ga = (const char*)(Ab + (m0 + row) * (long)lda + kt)
                       + (schx ^ ((row & 7) << 4));
      gld16(ga, (char*)lsA + i * 4096 + w * 1024);
    }
#pragma unroll
    for (int i = 0; i < 4; i++) {
      const int row = i * 32 + srow;
      const char* gb = (const char*)(Bb + (n0 + row) * (long)ldb + kt)
                       + (schx ^ ((row & 7) << 4));
      gld16(gb, (char*)lsB + i * 4096 + w * 1024);
    }
    __syncthreads();
#pragma unroll
    for (int h = 0; h < 2; h++) {
      bs8 af[4], bfr[4];
#pragma unroll
      for (int i = 0; i < 4; i++) {
        const int row = wr * 64 + i * 16 + (l & 15);
        const int byt = row * 128 + (((h * 64) + ((l >> 4) * 16)) ^ ((row & 7) << 4));
        af[i] = *(const bs8*)((const char*)lsA + byt);
      }
#pragma unroll
      for (int j = 0; j < 4; j++) {
        const int row = wc * 64 + j * 16 + (l & 15);
        const int byt = row * 128 + (((h * 64) + ((l >> 4) * 16)) ^ ((row & 7) << 4));
        bfr[j] = *(const bs8*)((const char*)lsB + byt);
      }
#pragma unroll
      for (int i = 0; i < 4; i++)
#pragma unroll
        for (int j = 0; j < 4; j++)
          acc[i][j] = __builtin_amdgcn_mfma_f32_16x16x32_bf16(af[i], bfr[j], acc[i][j], 0, 0, 0);
    }
    __syncthreads();
  }

  float bv[4] = {0.f, 0.f, 0.f, 0.f};
  if (bias) {
#pragma unroll
    for (int j = 0; j < 4; j++)
      bv[j] = inF(bias, (size_t)(n0 + wc * 64 + j * 16 + (l & 15)), bf);
  }
#pragma unroll
  for (int i = 0; i < 4; i++) {
#pragma unroll
    for (int j = 0; j < 4; j++) {
      const long rowb = m0 + wr * 64 + i * 16 + ((l >> 4) * 4);
      const long col = n0 + wc * 64 + j * 16 + (l & 15);
#pragma unroll
      for (int r = 0; r < 4; r++) {
        float v = acc[i][j][r] + bv[j];
        if (act == 1) v = tanhf(v);
        const long row = rowb + r;
        if (cmode == 0) {
          ((u16*)C)[bz * strideC + row * (long)ldc + col] = f2b(v);
        } else if (cmode == 1) {
          ((float*)C)[bz * strideC + row * (long)ldc + col] = v;
        } else {
          ((u16*)C)[((long)(row & 511) * 32 + (row >> 9)) * (long)ldc + col] = f2b(v);
        }
      }
    }
  }
}

// ---------------- masked softmax over T_ENC (in-place bf16) ----------------
__global__ __launch_bounds__(256) void k_softmax(
    u16* __restrict__ S, const int* __restrict__ lens) {
  const int m = blockIdx.x;
  const int b = m >> 9;
  const int len = lens[b];
  const int tid = threadIdx.x;
  const size_t base = (size_t)m * TENC;
  float v[4];
  float mx = -1e30f;
#pragma unroll
  for (int i = 0; i < 4; i++) {
    int j = tid + i * 256;
    float s = b2f(S[base + j]);
    v[i] = (j < len) ? s : -1e30f;
    mx = fmaxf(mx, v[i]);
  }
  __shared__ float red[8];
  for (int o = 32; o; o >>= 1) mx = fmaxf(mx, __shfl_xor(mx, o, 64));
  if ((tid & 63) == 0) red[tid >> 6] = mx;
  __syncthreads();
  mx = fmaxf(fmaxf(red[0], red[1]), fmaxf(red[2], red[3]));
  float e[4]; float sum = 0.f;
#pragma unroll
  for (int i = 0; i < 4; i++) {
    e[i] = (v[i] > -1e29f) ? expf(v[i] - mx) : 0.f;
    sum += e[i];
  }
  for (int o = 32; o; o >>= 1) sum += __shfl_xor(sum, o, 64);
  __shared__ float red2[8];
  if ((tid & 63) == 0) red2[tid >> 6] = sum;
  __syncthreads();
  sum = red2[0] + red2[1] + red2[2] + red2[3];
  const float inv = 1.f / sum;
#pragma unroll
  for (int i = 0; i < 4; i++) S[base + tid + i * 256] = f2b(e[i] * inv);
}

// ---------------- pack W_hh into per-block MFMA fragment order (K=1024) ----------------
// wpack[blk(256)][ks(32)][lane(64)][8] bf16 = 32KB/block, 8MB total.
// col c = lane&15: gate = c>>2 (0=r,1=z,2=n,3=zero), f = c&3; feature g = blk*4+f.
__global__ __launch_bounds__(256) void k_packw(
    const void* __restrict__ Whh, u16* __restrict__ out, const int* __restrict__ flagp) {
  const int bf = flagp[0];
  const long idx = (long)blockIdx.x * 256 + threadIdx.x;
  const int l = (int)(idx & 63);
  const int ks = (int)((idx >> 6) & 31);
  const int blk = (int)(idx >> 11);
  const int c = l & 15, gate = c >> 2, f = c & 3;
  const int g = blk * 4 + f;
  const int k = ks * 32 + ((l >> 4) << 3);
  const bool zero = (gate == 3);
  const long row = (long)gate * 1024 + g;
  u16 o[8];
#pragma unroll
  for (int e = 0; e < 8; e++)
    o[e] = zero ? (u16)0 : f2b(inF(Whh, (size_t)row * 1024 + k + e, bf));
  ushort4* dst = (ushort4*)(out + idx * 8);
  dst[0] = make_ushort4(o[0], o[1], o[2], o[3]);
  dst[1] = make_ushort4(o[4], o[5], o[6], o[7]);
}

// ---------------- one GRU step (K=1024, xp precomputed, round-2 structure) ----------------
// 256 blocks x 256 thr (4 waves = 4-way K-split). Block owns 4 features (16 cols).
__global__ __launch_bounds__(256) void k_gru(
    const u16* __restrict__ xp, const u16* __restrict__ wpack,
    const void* __restrict__ bhh, u16* __restrict__ y,
    const u16* __restrict__ hswz_r, u16* __restrict__ hswz_w,
    float* __restrict__ hf32, int t, const int* __restrict__ flagp) {
  __shared__ u16 hx[32768];      // 64KB swizzled h image
  __shared__ float red[2048];    // 8KB [w][mt][lane][4]
  const int bf = flagp[0];
  const int tid = threadIdx.x, l = tid & 63, w = tid >> 6;

  // stage h (linear 64KB copy; source stored in swizzled byte order)
#pragma unroll
  for (int i = 0; i < 16; i++) {
    const int off = i * 4096 + tid * 16;
    gld16((const char*)hswz_r + off, (char*)hx + off);
  }
  __syncthreads();

  f4_t S[2] = {};
  const u16* wp = wpack + (size_t)blockIdx.x * 16384;
#pragma unroll
  for (int s = 0; s < 8; s++) {
    const int ks = w * 8 + s;
    const bs8 bb = *(const bs8*)(wp + ((ks * 64 + l) << 3));
#pragma unroll
    for (int mt = 0; mt < 2; mt++) {
      const int row = mt * 16 + (l & 15);
      const int byt = row * 2048 + ((ks * 64 + ((l >> 4) << 4)) ^ ((row & 7) << 4));
      const bs8 aa = *(const bs8*)((const char*)hx + byt);
      S[mt] = __builtin_amdgcn_mfma_f32_16x16x32_bf16(aa, bb, S[mt], 0, 0, 0);
    }
  }
#pragma unroll
  for (int mt = 0; mt < 2; mt++)
    *(f4_t*)&red[((w * 2 + mt) * 64 + l) * 4] = S[mt];
  __syncthreads();

  if (tid < 128) {
    const int b = tid & 31, f = tid >> 5;
    const int g = blockIdx.x * 4 + f;
    const int mt = b >> 4, bl = b & 15, r = bl & 3;
    float gv[3];
#pragma unroll
    for (int c4 = 0; c4 < 3; c4++) {
      const int c = c4 * 4 + f;
      const int li = ((bl >> 2) << 4) | c;
      float s = 0.f;
#pragma unroll
      for (int ww = 0; ww < 4; ww++) s += red[((ww * 2 + mt) * 64 + li) * 4 + r];
      gv[c4] = s;
    }
    const float R = gv[0] + inF(bhh, (size_t)g, bf);
    const float Z = gv[1] + inF(bhh, (size_t)(1024 + g), bf);
    const float Nh = gv[2] + inF(bhh, (size_t)(2048 + g), bf);
    const long xb = (long)t * 98304 + (long)b * 3072 + g;
    const float xr = b2f(xp[xb]);
    const float xz = b2f(xp[xb + 1024]);
    const float xn = b2f(xp[xb + 2048]);
    const float rr = 1.f / (1.f + expf(-(xr + R)));
    const float zz = 1.f / (1.f + expf(-(xz + Z)));
    const float nn = tanhf(xn + rr * Nh);
    const float hp = hf32[b * 1024 + g];
    const float hv = (1.f - zz) * nn + zz * hp;
    hf32[b * 1024 + g] = hv;
    const u16 hb = f2b(hv);
    const int swb = b * 2048 + ((2 * g) ^ ((b & 7) << 4));
    hswz_w[swb >> 1] = hb;
    y[((long)b * 512 + t) * 1024 + g] = hb;
  }
}

// ---------------- log_softmax over V ----------------
__global__ __launch_bounds__(256) void k_logsoftmax(
    const float* __restrict__ L, void* __restrict__ out, const int* __restrict__ flagp) {
  const int bf = flagp[0];
  const int m = blockIdx.x;
  const int tid = threadIdx.x;
  const size_t base = (size_t)m * VOC;
  float v0 = L[base + tid], v1 = L[base + tid + 256];
  float mx = fmaxf(v0, v1);
  __shared__ float red[8];
  for (int o = 32; o; o >>= 1) mx = fmaxf(mx, __shfl_xor(mx, o, 64));
  if ((tid & 63) == 0) red[tid >> 6] = mx;
  __syncthreads();
  mx = fmaxf(fmaxf(red[0], red[1]), fmaxf(red[2], red[3]));
  float s = expf(v0 - mx) + expf(v1 - mx);
  for (int o = 32; o; o >>= 1) s += __shfl_xor(s, o, 64);
  __shared__ float red2[8];
  if ((tid & 63) == 0) red2[tid >> 6] = s;
  __syncthreads();
  s = red2[0] + red2[1] + red2[2] + red2[3];
  const float lse = mx + logf(s);
  outF(out, base + tid, v0 - lse, bf);
  outF(out, base + tid + 256, v1 - lse, bf);
}

extern "C" void kernel_launch(void* const* d_in, const int* in_sizes, int n_in,
                              void* d_out, int out_size, void* d_ws, size_t ws_size,
                              hipStream_t stream) {
  const void* enc = d_in[0];
  const int* lens = (const int*)d_in[1];
  const int* labels = (const int*)d_in[2];
  const void* emb = d_in[3];
  const void* lin_in = d_in[4];
  const void* lin_out = d_in[5];
  const void* w_ih0 = d_in[6];
  const void* w_hh0 = d_in[7];
  const void* b_ih0 = d_in[8];
  const void* b_hh0 = d_in[9];
  const void* w_ih1 = d_in[10];
  const void* w_hh1 = d_in[11];
  const void* b_ih1 = d_in[12];
  const void* b_hh1 = d_in[13];
  const void* fc_w = d_in[14];
  const void* fc_b = d_in[15];

  char* ws = (char*)d_ws;
  const size_t SZ = (size_t)NB * TSEQ * HD * 2;   // 33,554,432
  int* flag = (int*)ws;
  u16* R0 = (u16*)(ws + 256);                     // x -> encT -> attn -> wih1_bf
  u16* R1 = (u16*)(ws + 256 + SZ);                // enc_bf -> wih0_bf -> y0
  u16* R2 = (u16*)(ws + 256 + 2 * SZ);            // combined -> [y1 | packs + h]
  char* R4 = ws + 256 + 4 * SZ;                   // scores+wli/wlo -> xp0 -> xp1 -> wfc+logits

  char* R2u = (char*)R2 + SZ;
  u16* wpk0 = (u16*)R2u;                          // 8 MB (256 blk x 32KB)
  u16* wpk1 = (u16*)(R2u + 8388608);              // 8 MB
  char* hreg = R2u + 16777216;
  u16* h0swz = (u16*)hreg;                        // 2 x 64KB parity
  u16* h1swz = (u16*)(hreg + 131072);             // 2 x 64KB parity
  float* h0f32 = (float*)(hreg + 262144);         // 128KB
  float* h1f32 = (float*)(hreg + 393216);         // 128KB
  const size_t h_bytes = 524288;

  u16* scores = (u16*)R4;
  u16* wli = (u16*)(R4 + 35651584);
  u16* wlo = (u16*)(R4 + 37748736);
  u16* xp0 = (u16*)R4;                            // [t][b][3072] bf16, 96MB
  u16* xp1 = (u16*)R4;                            // same region (xp0 dead after L0)
  u16* wfc = (u16*)R4;                            // post-GRU, 1MB
  float* logits = (float*)(R4 + 1048576);         // post-GRU, 33.5MB f32

  k_detect<<<1, 256, 0, stream>>>((const u32*)emb, flag);
  k_embed<<<NB * TSEQ, 256, 0, stream>>>(labels, emb, R0, flag);
  k_f2bf<<<32768, 256, 0, stream>>>(enc, R1, flag);
  k_f2bf<<<1024, 256, 0, stream>>>(lin_in, wli, flag);
  k_f2bf<<<2048, 256, 0, stream>>>(lin_out, wlo, flag);

  // q = x @ lin_in^T -> combined right half
  k_mfma_gemm<<<dim3(128, 8, 1), 256, 0, stream>>>(
      R0, wli, HD, HD, HD, 0, 0, 0, (void*)(R2 + 1024), 2 * HD, 0, 0, nullptr, flag);
  // encT (x dead)
  k_transpose<<<dim3(32, 32, NB), 256, 0, stream>>>(enc, R0, flag);
  // scores[b] = q[b] @ enc_bf[b]^T
  k_mfma_gemm<<<dim3(4, 8, NB), 256, 0, stream>>>(
      R2 + 1024, R1, HD, 2 * HD, HD,
      (long)TSEQ * 2 * HD, (long)TENC * HD, (long)TSEQ * TENC,
      (void*)scores, TENC, 0, 0, nullptr, flag);
  k_softmax<<<NB * TSEQ, 256, 0, stream>>>(scores, lens);
  // mix[b] = w[b] @ encT[b]^T -> combined left half
  k_mfma_gemm<<<dim3(4, 8, NB), 256, 0, stream>>>(
      scores, R0, TENC, TENC, TENC,
      (long)TSEQ * TENC, (long)HD * TENC, (long)TSEQ * 2 * HD,
      (void*)R2, 2 * HD, 0, 0, nullptr, flag);
  // attn = tanh(combined @ lin_out^T) -> R0 row-major (encT dead)
  k_mfma_gemm<<<dim3(128, 8, 1), 256, 0, stream>>>(
      R2, wlo, 2 * HD, 2 * HD, 2 * HD, 0, 0, 0,
      (void*)R0, HD, 0, 1, nullptr, flag);

  // weight packs (combined dead -> R2 upper free)
  k_packw<<<2048, 256, 0, stream>>>(w_hh0, wpk0, flag);
  k_packw<<<2048, 256, 0, stream>>>(w_hh1, wpk1, flag);
  // w_ih0 bf16 (enc_bf dead)
  k_f2bf<<<3072, 256, 0, stream>>>(w_ih0, R1, flag);
  // xp0 = attn @ w_ih0^T + b_ih0, t-major (overwrites scores/wli/wlo - all dead)
  k_mfma_gemm<<<dim3(128, 24, 1), 256, 0, stream>>>(
      R0, R1, HD, HD, HD, 0, 0, 0, (void*)xp0, 3 * HD, 2, 0, b_ih0, flag);

  hipMemsetAsync(hreg, 0, h_bytes, stream);

  // GRU layer 0: y0 -> R1 (wih0_bf dead)
  for (int t = 0; t < TSEQ; ++t)
    k_gru<<<256, 256, 0, stream>>>(
        xp0, wpk0, b_hh0, R1,
        h0swz + (t & 1) * 32768, h0swz + ((t + 1) & 1) * 32768, h0f32, t, flag);

  // xp1 = y0 @ w_ih1^T + b_ih1, t-major (attn dead -> wih1_bf in R0; xp0 dead)
  k_f2bf<<<3072, 256, 0, stream>>>(w_ih1, R0, flag);
  k_mfma_gemm<<<dim3(128, 24, 1), 256, 0, stream>>>(
      R1, R0, HD, HD, HD, 0, 0, 0, (void*)xp1, 3 * HD, 2, 0, b_ih1, flag);

  // GRU layer 1: y1 -> R2 lower
  for (int t = 0; t < TSEQ; ++t)
    k_gru<<<256, 256, 0, stream>>>(
        xp1, wpk1, b_hh1, R2,
        h1swz + (t & 1) * 32768, h1swz + ((t + 1) & 1) * 32768, h1f32, t, flag);

  // logits = y1 @ fc_w^T + fc_b (xp1 dead)
  k_f2bf<<<512, 256, 0, stream>>>(fc_w, wfc, flag);
  k_mfma_gemm<<<dim3(128, 4, 1), 256, 0, stream>>>(
      R2, wfc, HD, HD, HD, 0, 0, 0, (void*)logits, VOC, 1, 0, fc_b, flag);
  k_logsoftmax<<<NB * TSEQ, 256, 0, stream>>>(logits, d_out, flag);
}